// Round 1
// baseline (154.333 us; speedup 1.0000x reference)
//
#include <hip/hip_runtime.h>
#include <math.h>

// NeRF ray-march forward (MipRayMarcher2).
// B=4, R=65536, S=48. One 64-lane wave per ray, lanes 0..47 hold samples.
// Outputs flat-concatenated: rgb [nRays*3], depth [nRays], weights [nRays*47].

#define S_SAMPLES 48
#define S_INTERVALS 47

__device__ __forceinline__ unsigned f2u_sortable(float f) {
    unsigned u = __float_as_uint(f);
    return (u & 0x80000000u) ? ~u : (u | 0x80000000u);
}
__device__ __forceinline__ float u2f_sortable(unsigned u) {
    return (u & 0x80000000u) ? __uint_as_float(u ^ 0x80000000u)
                             : __uint_as_float(~u);
}

__global__ void init_ws_kernel(unsigned* ws) {
    ws[0] = 0xFFFFFFFFu;  // min identity (sortable-uint max)
    ws[1] = 0u;           // max identity
}

// depths are sorted along the sample axis, so global min/max reduce over
// the first/last sample of each ray only.
__global__ __launch_bounds__(256) void minmax_kernel(
    const float* __restrict__ depths, unsigned* __restrict__ ws, int nRays) {
    int tid = blockIdx.x * blockDim.x + threadIdx.x;
    int stride = gridDim.x * blockDim.x;
    float mn = INFINITY, mx = -INFINITY;
    for (int r = tid; r < nRays; r += stride) {
        size_t base = (size_t)r * S_SAMPLES;
        mn = fminf(mn, depths[base]);
        mx = fmaxf(mx, depths[base + S_SAMPLES - 1]);
    }
#pragma unroll
    for (int off = 32; off; off >>= 1) {
        mn = fminf(mn, __shfl_xor(mn, off));
        mx = fmaxf(mx, __shfl_xor(mx, off));
    }
    if ((threadIdx.x & 63) == 0) {
        atomicMin(&ws[0], f2u_sortable(mn));
        atomicMax(&ws[1], f2u_sortable(mx));
    }
}

__global__ __launch_bounds__(256) void raymarch_kernel(
    const float* __restrict__ colors,     // [nRays, 48, 3]
    const float* __restrict__ densities,  // [nRays, 48]
    const float* __restrict__ depths,     // [nRays, 48]
    const unsigned* __restrict__ ws,      // sortable-uint gmin/gmax
    float* __restrict__ out_rgb,          // [nRays, 3]
    float* __restrict__ out_depth,        // [nRays]
    float* __restrict__ out_w,            // [nRays, 47]
    int nRays) {
    const int lane = threadIdx.x & 63;
    const int ray = blockIdx.x * (blockDim.x >> 6) + (threadIdx.x >> 6);
    if (ray >= nRays) return;

    // ---- coalesced loads: lane s -> sample s ----
    float dep = 0.f, den = 0.f, c0 = 0.f, c1 = 0.f, c2 = 0.f;
    if (lane < S_SAMPLES) {
        size_t base = (size_t)ray * S_SAMPLES + lane;
        dep = depths[base];
        den = densities[base];
        size_t cb = (size_t)ray * (S_SAMPLES * 3) + lane * 3;
        c0 = colors[cb];
        c1 = colors[cb + 1];
        c2 = colors[cb + 2];
    }

    // ---- neighbor (sample s+1) via shuffle ----
    float depN = __shfl_down(dep, 1);
    float denN = __shfl_down(den, 1);
    float c0N = __shfl_down(c0, 1);
    float c1N = __shfl_down(c1, 1);
    float c2N = __shfl_down(c2, 1);

    // ---- per-interval quantities (valid for lane < 47) ----
    float delta = depN - dep;
    float dmid = 0.5f * (den + denN) - 1.0f;
    // stable softplus: max(x,0) + log1p(exp(-|x|))
    float sp = fmaxf(dmid, 0.f) + log1pf(expf(-fabsf(dmid)));
    float alpha = 1.f - expf(-sp * delta);

    // ---- exclusive cumprod of (1 - alpha + 1e-10) via prefix-product scan ----
    float g = (lane < S_INTERVALS) ? (1.f - alpha + 1e-10f) : 1.f;
    float p = g;
#pragma unroll
    for (int off = 1; off < 64; off <<= 1) {
        float t = __shfl_up(p, off);
        if (lane >= off) p *= t;
    }
    float T = __shfl_up(p, 1);
    if (lane == 0) T = 1.f;

    float w = (lane < S_INTERVALS) ? alpha * T : 0.f;
    if (lane < S_INTERVALS) out_w[(size_t)ray * S_INTERVALS + lane] = w;

    // ---- weighted sums ----
    float cm0 = 0.5f * (c0 + c0N);
    float cm1 = 0.5f * (c1 + c1N);
    float cm2 = 0.5f * (c2 + c2N);
    float dm = 0.5f * (dep + depN);

    float s0 = w * cm0, s1 = w * cm1, s2 = w * cm2, sw = w, sd = w * dm;
#pragma unroll
    for (int off = 32; off; off >>= 1) {
        s0 += __shfl_xor(s0, off);
        s1 += __shfl_xor(s1, off);
        s2 += __shfl_xor(s2, off);
        sw += __shfl_xor(sw, off);
        sd += __shfl_xor(sd, off);
    }

    if (lane == 0) {
        float gmin = u2f_sortable(ws[0]);
        float gmax = u2f_sortable(ws[1]);
        float d = sd / sw;
        if (isnan(d)) d = INFINITY;  // nan_to_num(nan=inf)
        d = fminf(fmaxf(d, gmin), gmax);
        size_t rb = (size_t)ray * 3;
        out_rgb[rb + 0] = s0 * 2.f - 1.f;
        out_rgb[rb + 1] = s1 * 2.f - 1.f;
        out_rgb[rb + 2] = s2 * 2.f - 1.f;
        out_depth[ray] = d;
    }
}

extern "C" void kernel_launch(void* const* d_in, const int* in_sizes, int n_in,
                              void* d_out, int out_size, void* d_ws, size_t ws_size,
                              hipStream_t stream) {
    const float* colors = (const float*)d_in[0];
    const float* densities = (const float*)d_in[1];
    const float* depths = (const float*)d_in[2];

    const int nRays = in_sizes[2] / S_SAMPLES;  // 262144

    float* out = (float*)d_out;
    float* out_rgb = out;                        // nRays*3
    float* out_depth = out + (size_t)nRays * 3;  // nRays
    float* out_w = out + (size_t)nRays * 4;      // nRays*47

    unsigned* ws = (unsigned*)d_ws;

    init_ws_kernel<<<1, 1, 0, stream>>>(ws);
    minmax_kernel<<<256, 256, 0, stream>>>(depths, ws, nRays);

    const int wavesPerBlock = 4;  // 256 threads
    const int nBlocks = (nRays + wavesPerBlock - 1) / wavesPerBlock;
    raymarch_kernel<<<nBlocks, 256, 0, stream>>>(
        colors, densities, depths, ws, out_rgb, out_depth, out_w, nRays);
}